// Round 1
// baseline (6464.579 us; speedup 1.0000x reference)
//
#include <hip/hip_runtime.h>

#define NN 50000
#define NE 800000
#define FIN 64
#define H 128
#define NG 16

// ---------------- degree / norm ----------------
__global__ __launch_bounds__(256) void deg_init_kernel(float* __restrict__ deg) {
    int i = blockIdx.x * 256 + threadIdx.x;
    if (i < NN) deg[i] = 1.0f;  // self-loop
}

__global__ __launch_bounds__(256) void deg_add_kernel(const int* __restrict__ dst,
                                                      float* __restrict__ deg) {
    int e = blockIdx.x * 256 + threadIdx.x;
    if (e < NE) atomicAdd(&deg[dst[e]], 1.0f);
}

__global__ __launch_bounds__(256) void rsqrt_kernel(float* __restrict__ deg) {
    int i = blockIdx.x * 256 + threadIdx.x;
    if (i < NN) deg[i] = rsqrtf(deg[i]);
}

// ---------------- GEMM: out[N,H] = f(hin)[N,K] @ W[K,H] ----------------
// f(v) = bias ? relu(v + bias) : v   (fused previous-layer epilogue)
// Block: 256 threads -> 16 rows x 128 cols. W staged in LDS in 64-row halves
// (keeps static LDS under 64KB). Thread: 1 row x 8 cols (cg*4 and cg*4+64).
template <int K>
__global__ __launch_bounds__(256) void gemm_kernel(const float* __restrict__ hin,
                                                   const float* __restrict__ W,
                                                   const float* __restrict__ bias,
                                                   float* __restrict__ out) {
    __shared__ float Ws[64 * H];          // 32 KB
    __shared__ float hs[16 * (K + 4)];    // padded rows: break bank aliasing
    const int tid = threadIdx.x;
    const int row0 = blockIdx.x * 16;

    // stage input tile (16 x K), applying fused bias+relu
    for (int i = tid * 4; i < 16 * K; i += 1024) {
        int r = i / K, k = i % K;  // k multiple of 4
        float4 v = *(const float4*)&hin[(row0 + r) * K + k];
        if (bias) {
            float4 b = *(const float4*)&bias[k];
            v.x = fmaxf(v.x + b.x, 0.f);
            v.y = fmaxf(v.y + b.y, 0.f);
            v.z = fmaxf(v.z + b.z, 0.f);
            v.w = fmaxf(v.w + b.w, 0.f);
        }
        *(float4*)&hs[r * (K + 4) + k] = v;
    }

    const int r = tid >> 4;
    const int cg = tid & 15;
    const int c0 = cg * 4, c1 = c0 + 64;
    float4 acc0 = {0.f, 0.f, 0.f, 0.f}, acc1 = {0.f, 0.f, 0.f, 0.f};
    const float* hr = &hs[r * (K + 4)];

    for (int kb = 0; kb < K; kb += 64) {
        __syncthreads();
        for (int i = tid * 4; i < 64 * H; i += 1024)
            *(float4*)&Ws[i] = *(const float4*)&W[kb * H + i];
        __syncthreads();
#pragma unroll 8
        for (int k = 0; k < 64; k++) {
            float a = hr[kb + k];
            float4 w0 = *(const float4*)&Ws[k * H + c0];
            float4 w1 = *(const float4*)&Ws[k * H + c1];
            acc0.x += a * w0.x; acc0.y += a * w0.y;
            acc0.z += a * w0.z; acc0.w += a * w0.w;
            acc1.x += a * w1.x; acc1.y += a * w1.y;
            acc1.z += a * w1.z; acc1.w += a * w1.w;
        }
    }
    int row = row0 + r;
    *(float4*)&out[row * H + c0] = acc0;
    *(float4*)&out[row * H + c1] = acc1;
}

// ---------------- self-loop init: agg = hw * dinv^2 ----------------
__global__ __launch_bounds__(256) void self_init_kernel(const float* __restrict__ hw,
                                                        const float* __restrict__ dinv,
                                                        float* __restrict__ agg) {
    int idx = blockIdx.x * 256 + threadIdx.x;  // NN*32 items
    int n = idx >> 5, c = (idx & 31) << 2;
    if (n >= NN) return;
    float di = dinv[n];
    float s = di * di;
    float4 v = *(const float4*)&hw[n * H + c];
    v.x *= s; v.y *= s; v.z *= s; v.w *= s;
    *(float4*)&agg[n * H + c] = v;
}

// ---------------- edge scatter: agg[dst] += hw[src] * norm ----------------
__global__ __launch_bounds__(256) void scatter_kernel(const float* __restrict__ hw,
                                                      const int* __restrict__ ei,
                                                      const float* __restrict__ dinv,
                                                      float* __restrict__ agg) {
    int idx = blockIdx.x * 256 + threadIdx.x;  // NE*32 items
    int e = idx >> 5;
    if (e >= NE) return;
    int c = (idx & 31) << 2;
    int s = ei[e], d = ei[NE + e];
    float nm = dinv[s] * dinv[d];
    float4 v = *(const float4*)&hw[s * H + c];
    float* a = &agg[d * H + c];
    atomicAdd(a + 0, v.x * nm);
    atomicAdd(a + 1, v.y * nm);
    atomicAdd(a + 2, v.z * nm);
    atomicAdd(a + 3, v.w * nm);
}

// ---------------- pooling ----------------
__global__ __launch_bounds__(256) void pool_zero_kernel(float* __restrict__ p) {
    int i = blockIdx.x * 256 + threadIdx.x;
    if (i < NG * H + NG) p[i] = 0.f;
}

__global__ __launch_bounds__(256) void pool_kernel(const float* __restrict__ h,
                                                   const float* __restrict__ b4,
                                                   const int* __restrict__ batch,
                                                   float* __restrict__ pooled,
                                                   float* __restrict__ cnt) {
    int idx = blockIdx.x * 256 + threadIdx.x;  // NN*32
    int n = idx >> 5;
    if (n >= NN) return;
    int c = (idx & 31) << 2;
    int g = batch[n];
    float4 v = *(const float4*)&h[n * H + c];
    float4 b = *(const float4*)&b4[c];
    float* p = &pooled[g * H + c];
    atomicAdd(p + 0, v.x + b.x);
    atomicAdd(p + 1, v.y + b.y);
    atomicAdd(p + 2, v.z + b.z);
    atomicAdd(p + 3, v.w + b.w);
    if ((idx & 31) == 0) atomicAdd(&cnt[g], 1.0f);
}

// ---------------- final MLP (single block) ----------------
__global__ __launch_bounds__(1024) void mlp_kernel(const float* __restrict__ pooled,
                                                   const float* __restrict__ cnt,
                                                   const float* __restrict__ lw1,
                                                   const float* __restrict__ lb1,
                                                   const float* __restrict__ lw2,
                                                   const float* __restrict__ lb2,
                                                   float* __restrict__ out) {
    __shared__ float mean_s[NG * H];
    __shared__ float hid_s[NG * 64];
    int tid = threadIdx.x;
    for (int i = tid; i < NG * H; i += 1024) {
        int g = i >> 7;
        mean_s[i] = pooled[i] / fmaxf(cnt[g], 1.0f);
    }
    __syncthreads();
    {
        int g = tid >> 6, j = tid & 63;
        float acc = lb1[j];
        for (int f = 0; f < H; f++) acc += mean_s[g * H + f] * lw1[f * 64 + j];
        hid_s[g * 64 + j] = fmaxf(acc, 0.f);
    }
    __syncthreads();
    if (tid < 32) {
        int g = tid >> 1, c = tid & 1;
        float acc = lb2[c];
        for (int j = 0; j < 64; j++) acc += hid_s[g * 64 + j] * lw2[j * 2 + c];
        out[g * 2 + c] = acc;
    }
}

extern "C" void kernel_launch(void* const* d_in, const int* in_sizes, int n_in,
                              void* d_out, int out_size, void* d_ws, size_t ws_size,
                              hipStream_t stream) {
    const float* x = (const float*)d_in[0];
    const int* ei = (const int*)d_in[1];
    const int* batch = (const int*)d_in[2];
    const float* W1 = (const float*)d_in[3];
    const float* b1 = (const float*)d_in[4];
    const float* W2 = (const float*)d_in[5];
    const float* b2 = (const float*)d_in[6];
    const float* W3 = (const float*)d_in[7];
    const float* b3 = (const float*)d_in[8];
    const float* W4 = (const float*)d_in[9];
    const float* b4 = (const float*)d_in[10];
    const float* lw1 = (const float*)d_in[11];
    const float* lb1 = (const float*)d_in[12];
    const float* lw2 = (const float*)d_in[13];
    const float* lb2 = (const float*)d_in[14];
    float* out = (float*)d_out;

    float* ws = (float*)d_ws;
    float* dinv = ws;                       // NN
    float* bufA = ws + 50048;               // NN*H (hw)
    float* bufB = bufA + NN * H;            // NN*H (agg / next h)
    float* pooled = bufB + NN * H;          // NG*H
    float* cnt = pooled + NG * H;           // NG

    const int nodeBlocks = (NN + 255) / 256;      // 196
    const int edgeBlocks = (NE + 255) / 256;      // 3125
    const int nodeChunkBlocks = NN * 32 / 256;    // 6250 (exact)
    const int edgeChunkBlocks = NE * 32 / 256;    // 100000 (exact)
    const int gemmBlocks = NN / 16;               // 3125 (exact)

    // norm (once, reused by all 4 layers)
    deg_init_kernel<<<nodeBlocks, 256, 0, stream>>>(dinv);
    deg_add_kernel<<<edgeBlocks, 256, 0, stream>>>(ei + NE, dinv);
    rsqrt_kernel<<<nodeBlocks, 256, 0, stream>>>(dinv);

    // layer 1 (K=64, input x, no fused epilogue)
    gemm_kernel<FIN><<<gemmBlocks, 256, 0, stream>>>(x, W1, nullptr, bufA);
    self_init_kernel<<<nodeChunkBlocks, 256, 0, stream>>>(bufA, dinv, bufB);
    scatter_kernel<<<edgeChunkBlocks, 256, 0, stream>>>(bufA, ei, dinv, bufB);

    // layer 2 (fused relu(h + b1) on GEMM input read)
    gemm_kernel<H><<<gemmBlocks, 256, 0, stream>>>(bufB, W2, b1, bufA);
    self_init_kernel<<<nodeChunkBlocks, 256, 0, stream>>>(bufA, dinv, bufB);
    scatter_kernel<<<edgeChunkBlocks, 256, 0, stream>>>(bufA, ei, dinv, bufB);

    // layer 3
    gemm_kernel<H><<<gemmBlocks, 256, 0, stream>>>(bufB, W3, b2, bufA);
    self_init_kernel<<<nodeChunkBlocks, 256, 0, stream>>>(bufA, dinv, bufB);
    scatter_kernel<<<edgeChunkBlocks, 256, 0, stream>>>(bufA, ei, dinv, bufB);

    // layer 4
    gemm_kernel<H><<<gemmBlocks, 256, 0, stream>>>(bufB, W4, b3, bufA);
    self_init_kernel<<<nodeChunkBlocks, 256, 0, stream>>>(bufA, dinv, bufB);
    scatter_kernel<<<edgeChunkBlocks, 256, 0, stream>>>(bufA, ei, dinv, bufB);

    // pooling (fused +b4) + MLP
    pool_zero_kernel<<<(NG * H + NG + 255) / 256, 256, 0, stream>>>(pooled);
    pool_kernel<<<nodeChunkBlocks, 256, 0, stream>>>(bufB, b4, batch, pooled, cnt);
    mlp_kernel<<<1, 1024, 0, stream>>>(pooled, cnt, lw1, lb1, lw2, lb2, out);
}

// Round 2
// 1785.526 us; speedup vs baseline: 3.6205x; 3.6205x over previous
//
#include <hip/hip_runtime.h>

#define NN 50000
#define NE 800000
#define FIN 64
#define H 128
#define NG 16

// ================= CSR build =================
__global__ __launch_bounds__(256) void hist_kernel(const int* __restrict__ dst,
                                                   int* __restrict__ cnt) {
    int e = blockIdx.x * 256 + threadIdx.x;
    if (e < NE) atomicAdd(&cnt[dst[e]], 1);
}

// two-level exclusive scan over NN counts, single block of 1024 threads
__global__ __launch_bounds__(1024) void scan_kernel(const int* __restrict__ cnt,
                                                    int* __restrict__ rowptr,
                                                    int* __restrict__ cursor) {
    __shared__ int part[1024];
    const int t = threadIdx.x;
    const int CH = (NN + 1023) / 1024;  // 49
    int beg = t * CH, end = min(beg + CH, NN);
    int sum = 0;
    for (int i = beg; i < end; i++) sum += cnt[i];
    part[t] = sum;
    __syncthreads();
    for (int off = 1; off < 1024; off <<= 1) {
        int v = (t >= off) ? part[t - off] : 0;
        __syncthreads();
        part[t] += v;
        __syncthreads();
    }
    int ex = (t == 0) ? 0 : part[t - 1];
    for (int i = beg; i < end; i++) {
        rowptr[i] = ex;
        cursor[i] = ex;
        ex += cnt[i];
    }
    if (t == 0) rowptr[NN] = NE;
}

__global__ __launch_bounds__(256) void dinv_kernel(const int* __restrict__ cnt,
                                                   float* __restrict__ dinv) {
    int i = blockIdx.x * 256 + threadIdx.x;
    if (i < NN) dinv[i] = rsqrtf((float)cnt[i] + 1.0f);  // +1 self-loop
}

__global__ __launch_bounds__(256) void fill_kernel(const int* __restrict__ ei,
                                                   const float* __restrict__ dinv,
                                                   int* __restrict__ cursor,
                                                   int* __restrict__ csr_src,
                                                   float* __restrict__ csr_norm) {
    int e = blockIdx.x * 256 + threadIdx.x;
    if (e >= NE) return;
    int s = ei[e], d = ei[NE + e];
    int pos = atomicAdd(&cursor[d], 1);
    csr_src[pos] = s;
    csr_norm[pos] = dinv[s] * dinv[d];
}

// ================= GEMM: out[N,H] = f(hin)[N,K] @ W[K,H] =================
// f(v) = bias ? relu(v + bias) : v (fused previous-layer epilogue)
template <int K>
__global__ __launch_bounds__(256) void gemm_kernel(const float* __restrict__ hin,
                                                   const float* __restrict__ W,
                                                   const float* __restrict__ bias,
                                                   float* __restrict__ out) {
    __shared__ float Ws[64 * H];          // 32 KB
    __shared__ float hs[16 * (K + 4)];
    const int tid = threadIdx.x;
    const int row0 = blockIdx.x * 16;

    for (int i = tid * 4; i < 16 * K; i += 1024) {
        int r = i / K, k = i % K;
        float4 v = *(const float4*)&hin[(row0 + r) * K + k];
        if (bias) {
            float4 b = *(const float4*)&bias[k];
            v.x = fmaxf(v.x + b.x, 0.f);
            v.y = fmaxf(v.y + b.y, 0.f);
            v.z = fmaxf(v.z + b.z, 0.f);
            v.w = fmaxf(v.w + b.w, 0.f);
        }
        *(float4*)&hs[r * (K + 4) + k] = v;
    }

    const int r = tid >> 4;
    const int cg = tid & 15;
    const int c0 = cg * 4, c1 = c0 + 64;
    float4 acc0 = {0.f, 0.f, 0.f, 0.f}, acc1 = {0.f, 0.f, 0.f, 0.f};
    const float* hr = &hs[r * (K + 4)];

    for (int kb = 0; kb < K; kb += 64) {
        __syncthreads();
        for (int i = tid * 4; i < 64 * H; i += 1024)
            *(float4*)&Ws[i] = *(const float4*)&W[kb * H + i];
        __syncthreads();
#pragma unroll 8
        for (int k = 0; k < 64; k++) {
            float a = hr[kb + k];
            float4 w0 = *(const float4*)&Ws[k * H + c0];
            float4 w1 = *(const float4*)&Ws[k * H + c1];
            acc0.x += a * w0.x; acc0.y += a * w0.y;
            acc0.z += a * w0.z; acc0.w += a * w0.w;
            acc1.x += a * w1.x; acc1.y += a * w1.y;
            acc1.z += a * w1.z; acc1.w += a * w1.w;
        }
    }
    int row = row0 + r;
    *(float4*)&out[row * H + c0] = acc0;
    *(float4*)&out[row * H + c1] = acc1;
}

// ============ gather-side aggregation (fused self-loop) ============
// one wave per dst node; lane handles 2 consecutive feats (float2).
// agg[n] = hw[n]*dinv[n]^2 + sum_e hw[src_e]*norm_e
__global__ __launch_bounds__(256) void agg_kernel(const float* __restrict__ hw,
                                                  const int* __restrict__ rowptr,
                                                  const int* __restrict__ csr_src,
                                                  const float* __restrict__ csr_norm,
                                                  const float* __restrict__ dinv,
                                                  float* __restrict__ agg) {
    const int lane = threadIdx.x & 63;
    const int n = blockIdx.x * 4 + (threadIdx.x >> 6);
    const float2* __restrict__ hw2 = (const float2*)hw;

    float di = dinv[n];
    float s2 = di * di;
    float2 acc = hw2[n * 64 + lane];
    acc.x *= s2; acc.y *= s2;

    int beg = rowptr[n], end = rowptr[n + 1];
    for (int i = beg; i < end; i++) {
        int s = csr_src[i];
        float nm = csr_norm[i];
        float2 v = hw2[s * 64 + lane];
        acc.x += v.x * nm;
        acc.y += v.y * nm;
    }
    ((float2*)agg)[n * 64 + lane] = acc;
}

// ================= pooling =================
__global__ __launch_bounds__(256) void pool_kernel(const float* __restrict__ h,
                                                   const float* __restrict__ b4,
                                                   const int* __restrict__ batch,
                                                   float* __restrict__ pooled,
                                                   float* __restrict__ cnt) {
    int idx = blockIdx.x * 256 + threadIdx.x;  // NN*32
    int n = idx >> 5;
    if (n >= NN) return;
    int c = (idx & 31) << 2;
    int g = batch[n];
    float4 v = *(const float4*)&h[n * H + c];
    float4 b = *(const float4*)&b4[c];
    float* p = &pooled[g * H + c];
    atomicAdd(p + 0, v.x + b.x);
    atomicAdd(p + 1, v.y + b.y);
    atomicAdd(p + 2, v.z + b.z);
    atomicAdd(p + 3, v.w + b.w);
    if ((idx & 31) == 0) atomicAdd(&cnt[g], 1.0f);
}

// ================= final MLP (single block) =================
__global__ __launch_bounds__(1024) void mlp_kernel(const float* __restrict__ pooled,
                                                   const float* __restrict__ cnt,
                                                   const float* __restrict__ lw1,
                                                   const float* __restrict__ lb1,
                                                   const float* __restrict__ lw2,
                                                   const float* __restrict__ lb2,
                                                   float* __restrict__ out) {
    __shared__ float mean_s[NG * H];
    __shared__ float hid_s[NG * 64];
    int tid = threadIdx.x;
    for (int i = tid; i < NG * H; i += 1024) {
        int g = i >> 7;
        mean_s[i] = pooled[i] / fmaxf(cnt[g], 1.0f);
    }
    __syncthreads();
    {
        int g = tid >> 6, j = tid & 63;
        float acc = lb1[j];
        for (int f = 0; f < H; f++) acc += mean_s[g * H + f] * lw1[f * 64 + j];
        hid_s[g * 64 + j] = fmaxf(acc, 0.f);
    }
    __syncthreads();
    if (tid < 32) {
        int g = tid >> 1, c = tid & 1;
        float acc = lb2[c];
        for (int j = 0; j < 64; j++) acc += hid_s[g * 64 + j] * lw2[j * 2 + c];
        out[g * 2 + c] = acc;
    }
}

extern "C" void kernel_launch(void* const* d_in, const int* in_sizes, int n_in,
                              void* d_out, int out_size, void* d_ws, size_t ws_size,
                              hipStream_t stream) {
    const float* x = (const float*)d_in[0];
    const int* ei = (const int*)d_in[1];
    const int* batch = (const int*)d_in[2];
    const float* W1 = (const float*)d_in[3];
    const float* b1 = (const float*)d_in[4];
    const float* W2 = (const float*)d_in[5];
    const float* b2 = (const float*)d_in[6];
    const float* W3 = (const float*)d_in[7];
    const float* b3 = (const float*)d_in[8];
    const float* W4 = (const float*)d_in[9];
    const float* b4 = (const float*)d_in[10];
    const float* lw1 = (const float*)d_in[11];
    const float* lb1 = (const float*)d_in[12];
    const float* lw2 = (const float*)d_in[13];
    const float* lb2 = (const float*)d_in[14];
    float* out = (float*)d_out;

    // workspace layout (4-byte units)
    char* wsb = (char*)d_ws;
    int* cnt = (int*)wsb;                        // NN
    int* rowptr = cnt + NN;                      // NN+1 (pad to 50004)
    int* cursor = rowptr + 50004;                // NN
    int* csr_src = cursor + NN;                  // NE
    float* csr_norm = (float*)(csr_src + NE);    // NE
    float* dinv = csr_norm + NE;                 // NN
    float* bufA = dinv + NN;                     // NN*H
    float* bufB = bufA + NN * H;                 // NN*H
    float* pooled = bufB + NN * H;               // NG*H
    float* pcnt = pooled + NG * H;               // NG

    const int nodeBlocks = (NN + 255) / 256;   // 196
    const int edgeBlocks = (NE + 255) / 256;   // 3125
    const int nodeChunkBlocks = NN * 32 / 256; // 6250
    const int gemmBlocks = NN / 16;            // 3125
    const int aggBlocks = NN / 4;              // 12500

    // ---- CSR build (once; reused by all 4 layers) ----
    hipMemsetAsync(cnt, 0, NN * sizeof(int), stream);
    hist_kernel<<<edgeBlocks, 256, 0, stream>>>(ei + NE, cnt);
    scan_kernel<<<1, 1024, 0, stream>>>(cnt, rowptr, cursor);
    dinv_kernel<<<nodeBlocks, 256, 0, stream>>>(cnt, dinv);
    fill_kernel<<<edgeBlocks, 256, 0, stream>>>(ei, dinv, cursor, csr_src, csr_norm);

    // ---- layer 1 (K=64, input x) ----
    gemm_kernel<FIN><<<gemmBlocks, 256, 0, stream>>>(x, W1, nullptr, bufA);
    agg_kernel<<<aggBlocks, 256, 0, stream>>>(bufA, rowptr, csr_src, csr_norm, dinv, bufB);

    // ---- layer 2 (fused relu(h + b1) on GEMM input read) ----
    gemm_kernel<H><<<gemmBlocks, 256, 0, stream>>>(bufB, W2, b1, bufA);
    agg_kernel<<<aggBlocks, 256, 0, stream>>>(bufA, rowptr, csr_src, csr_norm, dinv, bufB);

    // ---- layer 3 ----
    gemm_kernel<H><<<gemmBlocks, 256, 0, stream>>>(bufB, W3, b2, bufA);
    agg_kernel<<<aggBlocks, 256, 0, stream>>>(bufA, rowptr, csr_src, csr_norm, dinv, bufB);

    // ---- layer 4 ----
    gemm_kernel<H><<<gemmBlocks, 256, 0, stream>>>(bufB, W4, b3, bufA);
    agg_kernel<<<aggBlocks, 256, 0, stream>>>(bufA, rowptr, csr_src, csr_norm, dinv, bufB);

    // ---- pooling (fused +b4) + MLP ----
    hipMemsetAsync(pooled, 0, (NG * H + NG) * sizeof(float), stream);
    pool_kernel<<<nodeChunkBlocks, 256, 0, stream>>>(bufB, b4, batch, pooled, pcnt);
    mlp_kernel<<<1, 1024, 0, stream>>>(pooled, pcnt, lw1, lb1, lw2, lb2, out);
}

// Round 3
// 828.067 us; speedup vs baseline: 7.8068x; 2.1563x over previous
//
#include <hip/hip_runtime.h>

#define NN 50000
#define NE 800000
#define FIN 64
#define H 128
#define NG 16
#define POOL_BLOCKS 200
#define POOL_NODES 250

// ================= CSR build =================
__global__ __launch_bounds__(256) void hist_kernel(const int* __restrict__ dst,
                                                   int* __restrict__ cnt) {
    int e = blockIdx.x * 256 + threadIdx.x;
    if (e < NE) atomicAdd(&cnt[dst[e]], 1);
}

// two-level exclusive scan over NN counts, single block of 1024 threads
__global__ __launch_bounds__(1024) void scan_kernel(const int* __restrict__ cnt,
                                                    int* __restrict__ rowptr,
                                                    int* __restrict__ cursor) {
    __shared__ int part[1024];
    const int t = threadIdx.x;
    const int CH = (NN + 1023) / 1024;  // 49
    int beg = t * CH, end = min(beg + CH, NN);
    int sum = 0;
    for (int i = beg; i < end; i++) sum += cnt[i];
    part[t] = sum;
    __syncthreads();
    for (int off = 1; off < 1024; off <<= 1) {
        int v = (t >= off) ? part[t - off] : 0;
        __syncthreads();
        part[t] += v;
        __syncthreads();
    }
    int ex = (t == 0) ? 0 : part[t - 1];
    for (int i = beg; i < end; i++) {
        rowptr[i] = ex;
        cursor[i] = ex;
        ex += cnt[i];
    }
    if (t == 0) rowptr[NN] = NE;
}

__global__ __launch_bounds__(256) void dinv_kernel(const int* __restrict__ cnt,
                                                   float* __restrict__ dinv) {
    int i = blockIdx.x * 256 + threadIdx.x;
    if (i < NN) dinv[i] = rsqrtf((float)cnt[i] + 1.0f);  // +1 self-loop
}

__global__ __launch_bounds__(256) void fill_kernel(const int* __restrict__ ei,
                                                   const float* __restrict__ dinv,
                                                   int* __restrict__ cursor,
                                                   int* __restrict__ csr_src,
                                                   float* __restrict__ csr_norm) {
    int e = blockIdx.x * 256 + threadIdx.x;
    if (e >= NE) return;
    int s = ei[e], d = ei[NE + e];
    int pos = atomicAdd(&cursor[d], 1);
    csr_src[pos] = s;
    csr_norm[pos] = dinv[s] * dinv[d];
}

// ================= GEMM: out[N,H] = f(hin)[N,K] @ W[K,H] =================
// f(v) = bias ? relu(v + bias) : v (fused previous-layer epilogue)
template <int K>
__global__ __launch_bounds__(256) void gemm_kernel(const float* __restrict__ hin,
                                                   const float* __restrict__ W,
                                                   const float* __restrict__ bias,
                                                   float* __restrict__ out) {
    __shared__ float Ws[64 * H];          // 32 KB
    __shared__ float hs[16 * (K + 4)];
    const int tid = threadIdx.x;
    const int row0 = blockIdx.x * 16;

    for (int i = tid * 4; i < 16 * K; i += 1024) {
        int r = i / K, k = i % K;
        float4 v = *(const float4*)&hin[(row0 + r) * K + k];
        if (bias) {
            float4 b = *(const float4*)&bias[k];
            v.x = fmaxf(v.x + b.x, 0.f);
            v.y = fmaxf(v.y + b.y, 0.f);
            v.z = fmaxf(v.z + b.z, 0.f);
            v.w = fmaxf(v.w + b.w, 0.f);
        }
        *(float4*)&hs[r * (K + 4) + k] = v;
    }

    const int r = tid >> 4;
    const int cg = tid & 15;
    const int c0 = cg * 4, c1 = c0 + 64;
    float4 acc0 = {0.f, 0.f, 0.f, 0.f}, acc1 = {0.f, 0.f, 0.f, 0.f};
    const float* hr = &hs[r * (K + 4)];

    for (int kb = 0; kb < K; kb += 64) {
        __syncthreads();
        for (int i = tid * 4; i < 64 * H; i += 1024)
            *(float4*)&Ws[i] = *(const float4*)&W[kb * H + i];
        __syncthreads();
#pragma unroll 8
        for (int k = 0; k < 64; k++) {
            float a = hr[kb + k];
            float4 w0 = *(const float4*)&Ws[k * H + c0];
            float4 w1 = *(const float4*)&Ws[k * H + c1];
            acc0.x += a * w0.x; acc0.y += a * w0.y;
            acc0.z += a * w0.z; acc0.w += a * w0.w;
            acc1.x += a * w1.x; acc1.y += a * w1.y;
            acc1.z += a * w1.z; acc1.w += a * w1.w;
        }
    }
    int row = row0 + r;
    *(float4*)&out[row * H + c0] = acc0;
    *(float4*)&out[row * H + c1] = acc1;
}

// ============ gather-side aggregation (fused self-loop) ============
// one wave per dst node; lane handles 2 consecutive feats (float2).
// agg[n] = hw[n]*dinv[n]^2 + sum_e hw[src_e]*norm_e
__global__ __launch_bounds__(256) void agg_kernel(const float* __restrict__ hw,
                                                  const int* __restrict__ rowptr,
                                                  const int* __restrict__ csr_src,
                                                  const float* __restrict__ csr_norm,
                                                  const float* __restrict__ dinv,
                                                  float* __restrict__ agg) {
    const int lane = threadIdx.x & 63;
    const int n = blockIdx.x * 4 + (threadIdx.x >> 6);
    const float2* __restrict__ hw2 = (const float2*)hw;

    float di = dinv[n];
    float s2 = di * di;
    float2 acc = hw2[n * 64 + lane];
    acc.x *= s2; acc.y *= s2;

    int beg = rowptr[n], end = rowptr[n + 1];
    for (int i = beg; i < end; i++) {
        int s = csr_src[i];
        float nm = csr_norm[i];
        float2 v = hw2[s * 64 + lane];
        acc.x += v.x * nm;
        acc.y += v.y * nm;
    }
    ((float2*)agg)[n * 64 + lane] = acc;
}

// ======== pooling: block-local segment reduction (batch is sorted) ========
// 200 blocks x 250 nodes. Thread owns float2 feature pair c2 = tid&63,
// row-group rsub = tid>>6 strides nodes by 4. Register-accumulate until the
// graph id changes, then one atomic per (segment, feature).
__global__ __launch_bounds__(256) void pool_kernel(const float* __restrict__ h,
                                                   const float* __restrict__ b4,
                                                   const int* __restrict__ batch,
                                                   float* __restrict__ pooled,
                                                   float* __restrict__ cnt) {
    __shared__ int bs[POOL_NODES];
    const int tid = threadIdx.x;
    const int n0 = blockIdx.x * POOL_NODES;
    for (int i = tid; i < POOL_NODES; i += 256) bs[i] = batch[n0 + i];
    __syncthreads();
    const int c2 = tid & 63;
    const int rsub = tid >> 6;  // 0..3
    const float2* __restrict__ h2 = (const float2*)h;
    float2 bb = ((const float2*)b4)[c2];
    float2 acc = {0.f, 0.f};
    float cacc = 0.f;
    int curg = bs[rsub];
    for (int r = rsub; r < POOL_NODES; r += 4) {
        int g = bs[r];
        if (g != curg) {
            atomicAdd(&pooled[curg * H + c2 * 2], acc.x);
            atomicAdd(&pooled[curg * H + c2 * 2 + 1], acc.y);
            if (c2 == 0) atomicAdd(&cnt[curg], cacc);
            acc.x = acc.y = 0.f;
            cacc = 0.f;
            curg = g;
        }
        float2 v = h2[(long)(n0 + r) * 64 + c2];
        acc.x += v.x + bb.x;
        acc.y += v.y + bb.y;
        cacc += 1.f;
    }
    atomicAdd(&pooled[curg * H + c2 * 2], acc.x);
    atomicAdd(&pooled[curg * H + c2 * 2 + 1], acc.y);
    if (c2 == 0) atomicAdd(&cnt[curg], cacc);
}

// ================= final MLP (single block) =================
__global__ __launch_bounds__(1024) void mlp_kernel(const float* __restrict__ pooled,
                                                   const float* __restrict__ cnt,
                                                   const float* __restrict__ lw1,
                                                   const float* __restrict__ lb1,
                                                   const float* __restrict__ lw2,
                                                   const float* __restrict__ lb2,
                                                   float* __restrict__ out) {
    __shared__ float mean_s[NG * H];
    __shared__ float hid_s[NG * 64];
    int tid = threadIdx.x;
    for (int i = tid; i < NG * H; i += 1024) {
        int g = i >> 7;
        mean_s[i] = pooled[i] / fmaxf(cnt[g], 1.0f);
    }
    __syncthreads();
    {
        int g = tid >> 6, j = tid & 63;
        float acc = lb1[j];
        for (int f = 0; f < H; f++) acc += mean_s[g * H + f] * lw1[f * 64 + j];
        hid_s[g * 64 + j] = fmaxf(acc, 0.f);
    }
    __syncthreads();
    if (tid < 32) {
        int g = tid >> 1, c = tid & 1;
        float acc = lb2[c];
        for (int j = 0; j < 64; j++) acc += hid_s[g * 64 + j] * lw2[j * 2 + c];
        out[g * 2 + c] = acc;
    }
}

extern "C" void kernel_launch(void* const* d_in, const int* in_sizes, int n_in,
                              void* d_out, int out_size, void* d_ws, size_t ws_size,
                              hipStream_t stream) {
    const float* x = (const float*)d_in[0];
    const int* ei = (const int*)d_in[1];
    const int* batch = (const int*)d_in[2];
    const float* W1 = (const float*)d_in[3];
    const float* b1 = (const float*)d_in[4];
    const float* W2 = (const float*)d_in[5];
    const float* b2 = (const float*)d_in[6];
    const float* W3 = (const float*)d_in[7];
    const float* b3 = (const float*)d_in[8];
    const float* W4 = (const float*)d_in[9];
    const float* b4 = (const float*)d_in[10];
    const float* lw1 = (const float*)d_in[11];
    const float* lb1 = (const float*)d_in[12];
    const float* lw2 = (const float*)d_in[13];
    const float* lb2 = (const float*)d_in[14];
    float* out = (float*)d_out;

    // workspace layout (4-byte units)
    char* wsb = (char*)d_ws;
    int* cnt = (int*)wsb;                        // NN
    int* rowptr = cnt + NN;                      // NN+1 (pad to 50004)
    int* cursor = rowptr + 50004;                // NN
    int* csr_src = cursor + NN;                  // NE
    float* csr_norm = (float*)(csr_src + NE);    // NE
    float* dinv = csr_norm + NE;                 // NN
    float* bufA = dinv + NN;                     // NN*H
    float* bufB = bufA + NN * H;                 // NN*H
    float* pooled = bufB + NN * H;               // NG*H
    float* pcnt = pooled + NG * H;               // NG

    const int nodeBlocks = (NN + 255) / 256;   // 196
    const int edgeBlocks = (NE + 255) / 256;   // 3125
    const int gemmBlocks = NN / 16;            // 3125
    const int aggBlocks = NN / 4;              // 12500

    // ---- CSR build (once; reused by all 4 layers) ----
    hipMemsetAsync(cnt, 0, NN * sizeof(int), stream);
    hist_kernel<<<edgeBlocks, 256, 0, stream>>>(ei + NE, cnt);
    scan_kernel<<<1, 1024, 0, stream>>>(cnt, rowptr, cursor);
    dinv_kernel<<<nodeBlocks, 256, 0, stream>>>(cnt, dinv);
    fill_kernel<<<edgeBlocks, 256, 0, stream>>>(ei, dinv, cursor, csr_src, csr_norm);

    // ---- layer 1 (K=64, input x) ----
    gemm_kernel<FIN><<<gemmBlocks, 256, 0, stream>>>(x, W1, nullptr, bufA);
    agg_kernel<<<aggBlocks, 256, 0, stream>>>(bufA, rowptr, csr_src, csr_norm, dinv, bufB);

    // ---- layer 2 (fused relu(h + b1) on GEMM input read) ----
    gemm_kernel<H><<<gemmBlocks, 256, 0, stream>>>(bufB, W2, b1, bufA);
    agg_kernel<<<aggBlocks, 256, 0, stream>>>(bufA, rowptr, csr_src, csr_norm, dinv, bufB);

    // ---- layer 3 ----
    gemm_kernel<H><<<gemmBlocks, 256, 0, stream>>>(bufB, W3, b2, bufA);
    agg_kernel<<<aggBlocks, 256, 0, stream>>>(bufA, rowptr, csr_src, csr_norm, dinv, bufB);

    // ---- layer 4 ----
    gemm_kernel<H><<<gemmBlocks, 256, 0, stream>>>(bufB, W4, b3, bufA);
    agg_kernel<<<aggBlocks, 256, 0, stream>>>(bufA, rowptr, csr_src, csr_norm, dinv, bufB);

    // ---- pooling (fused +b4) + MLP ----
    hipMemsetAsync(pooled, 0, (NG * H + NG) * sizeof(float), stream);
    pool_kernel<<<POOL_BLOCKS, 256, 0, stream>>>(bufB, b4, batch, pooled, pcnt);
    mlp_kernel<<<1, 1024, 0, stream>>>(pooled, pcnt, lw1, lb1, lw2, lb2, out);
}

// Round 4
// 509.308 us; speedup vs baseline: 12.6929x; 1.6259x over previous
//
#include <hip/hip_runtime.h>

#define NN 50000
#define NE 800000
#define FIN 64
#define H 128
#define NG 16
#define POOL_BLOCKS 200
#define POOL_NODES 250
#define SCAN_BLOCKS 196  // ceil(NN/256)

// ---- helpers ----
__device__ inline unsigned int pack_bf16x2(float a, float b) {
    unsigned int ua = __float_as_uint(a), ub = __float_as_uint(b);
    unsigned int lo = (ua + 0x7fffu + ((ua >> 16) & 1u)) >> 16;
    unsigned int hi = (ub + 0x7fffu + ((ub >> 16) & 1u)) & 0xffff0000u;
    return lo | hi;
}

// ================= CSR build =================
__global__ __launch_bounds__(256) void hist_kernel(const int* __restrict__ dst,
                                                   int* __restrict__ cnt) {
    int e = blockIdx.x * 256 + threadIdx.x;
    if (e < NE) atomicAdd(&cnt[dst[e]], 1);
}

// scan A: per-block (256-wide) sum of cnt -> bsum[block]
__global__ __launch_bounds__(256) void scanA_kernel(const int* __restrict__ cnt,
                                                    int* __restrict__ bsum) {
    __shared__ int red[4];
    int i = blockIdx.x * 256 + threadIdx.x;
    int v = (i < NN) ? cnt[i] : 0;
    for (int off = 32; off > 0; off >>= 1) v += __shfl_down(v, off);
    if ((threadIdx.x & 63) == 0) red[threadIdx.x >> 6] = v;
    __syncthreads();
    if (threadIdx.x == 0) bsum[blockIdx.x] = red[0] + red[1] + red[2] + red[3];
}

// scan B: exclusive scan of the SCAN_BLOCKS partials (single 256-thread block)
__global__ __launch_bounds__(256) void scanB_kernel(int* __restrict__ bsum) {
    __shared__ int s[256];
    int t = threadIdx.x;
    int v = (t < SCAN_BLOCKS) ? bsum[t] : 0;
    s[t] = v;
    __syncthreads();
    for (int off = 1; off < 256; off <<= 1) {
        int u = (t >= off) ? s[t - off] : 0;
        __syncthreads();
        s[t] += u;
        __syncthreads();
    }
    if (t < SCAN_BLOCKS) bsum[t] = s[t] - v;  // exclusive
}

// scan C: per-block local exclusive scan + global base -> rowptr, cursor
__global__ __launch_bounds__(256) void scanC_kernel(const int* __restrict__ cnt,
                                                    const int* __restrict__ bsum,
                                                    int* __restrict__ rowptr,
                                                    int* __restrict__ cursor) {
    __shared__ int s[256];
    int t = threadIdx.x;
    int i = blockIdx.x * 256 + t;
    int v = (i < NN) ? cnt[i] : 0;
    s[t] = v;
    __syncthreads();
    for (int off = 1; off < 256; off <<= 1) {
        int u = (t >= off) ? s[t - off] : 0;
        __syncthreads();
        s[t] += u;
        __syncthreads();
    }
    if (i < NN) {
        int ex = bsum[blockIdx.x] + s[t] - v;
        rowptr[i] = ex;
        cursor[i] = ex;
    }
    if (i == NN - 1) rowptr[NN] = NE;
}

__global__ __launch_bounds__(256) void dinv_kernel(const int* __restrict__ cnt,
                                                   float* __restrict__ dinv) {
    int i = blockIdx.x * 256 + threadIdx.x;
    if (i < NN) dinv[i] = rsqrtf((float)cnt[i] + 1.0f);  // +1 self-loop
}

// fill: packed (src, norm) per edge -> one 8B scattered store
__global__ __launch_bounds__(256) void fill_kernel(const int* __restrict__ ei,
                                                   const float* __restrict__ dinv,
                                                   int* __restrict__ cursor,
                                                   int2* __restrict__ csr) {
    int e = blockIdx.x * 256 + threadIdx.x;
    if (e >= NE) return;
    int s = ei[e], d = ei[NE + e];
    int pos = atomicAdd(&cursor[d], 1);
    csr[pos] = make_int2(s, __float_as_int(dinv[s] * dinv[d]));
}

// ======= GEMM: out_bf16[N,H] = f(hin)[N,K] @ W[K,H], fp32 accumulate =======
// f(v) = bias ? relu(v + bias) : v (fused previous-layer epilogue)
template <int K>
__global__ __launch_bounds__(256) void gemm_kernel(const float* __restrict__ hin,
                                                   const float* __restrict__ W,
                                                   const float* __restrict__ bias,
                                                   unsigned int* __restrict__ out) {
    __shared__ float Ws[64 * H];          // 32 KB
    __shared__ float hs[16 * (K + 4)];
    const int tid = threadIdx.x;
    const int row0 = blockIdx.x * 16;

    for (int i = tid * 4; i < 16 * K; i += 1024) {
        int r = i / K, k = i % K;
        float4 v = *(const float4*)&hin[(row0 + r) * K + k];
        if (bias) {
            float4 b = *(const float4*)&bias[k];
            v.x = fmaxf(v.x + b.x, 0.f);
            v.y = fmaxf(v.y + b.y, 0.f);
            v.z = fmaxf(v.z + b.z, 0.f);
            v.w = fmaxf(v.w + b.w, 0.f);
        }
        *(float4*)&hs[r * (K + 4) + k] = v;
    }

    const int r = tid >> 4;
    const int cg = tid & 15;
    const int c0 = cg * 4, c1 = c0 + 64;
    float4 acc0 = {0.f, 0.f, 0.f, 0.f}, acc1 = {0.f, 0.f, 0.f, 0.f};
    const float* hr = &hs[r * (K + 4)];

    for (int kb = 0; kb < K; kb += 64) {
        __syncthreads();
        for (int i = tid * 4; i < 64 * H; i += 1024)
            *(float4*)&Ws[i] = *(const float4*)&W[kb * H + i];
        __syncthreads();
#pragma unroll 8
        for (int k = 0; k < 64; k++) {
            float a = hr[kb + k];
            float4 w0 = *(const float4*)&Ws[k * H + c0];
            float4 w1 = *(const float4*)&Ws[k * H + c1];
            acc0.x += a * w0.x; acc0.y += a * w0.y;
            acc0.z += a * w0.z; acc0.w += a * w0.w;
            acc1.x += a * w1.x; acc1.y += a * w1.y;
            acc1.z += a * w1.z; acc1.w += a * w1.w;
        }
    }
    int row = row0 + r;
    uint2 q0 = {pack_bf16x2(acc0.x, acc0.y), pack_bf16x2(acc0.z, acc0.w)};
    uint2 q1 = {pack_bf16x2(acc1.x, acc1.y), pack_bf16x2(acc1.z, acc1.w)};
    *(uint2*)&out[row * 64 + cg * 2] = q0;
    *(uint2*)&out[row * 64 + 32 + cg * 2] = q1;
}

// ============ gather-side aggregation (fused self-loop), bf16 hw ============
// one wave per dst node; lane holds a bf16x2 feature pair; fp32 accumulate.
// agg[n] = hw[n]*dinv[n]^2 + sum_e hw[src_e]*norm_e
__device__ inline float bf_lo(unsigned int u) { return __uint_as_float(u << 16); }
__device__ inline float bf_hi(unsigned int u) { return __uint_as_float(u & 0xffff0000u); }

__global__ __launch_bounds__(256) void agg_kernel(const unsigned int* __restrict__ hwb,
                                                  const int* __restrict__ rowptr,
                                                  const int2* __restrict__ csr,
                                                  const float* __restrict__ dinv,
                                                  float* __restrict__ agg) {
    const int lane = threadIdx.x & 63;
    const int n = blockIdx.x * 4 + (threadIdx.x >> 6);

    float di = dinv[n];
    float s2 = di * di;
    unsigned int u = hwb[n * 64 + lane];
    float ax = bf_lo(u) * s2, ay = bf_hi(u) * s2;

    int beg = rowptr[n], end = rowptr[n + 1];
    int i = beg;
    for (; i + 4 <= end; i += 4) {
        int2 e0 = csr[i], e1 = csr[i + 1], e2 = csr[i + 2], e3 = csr[i + 3];
        unsigned int u0 = hwb[e0.x * 64 + lane];
        unsigned int u1 = hwb[e1.x * 64 + lane];
        unsigned int u2 = hwb[e2.x * 64 + lane];
        unsigned int u3 = hwb[e3.x * 64 + lane];
        float n0 = __int_as_float(e0.y), n1 = __int_as_float(e1.y);
        float n2 = __int_as_float(e2.y), n3 = __int_as_float(e3.y);
        ax += bf_lo(u0) * n0; ay += bf_hi(u0) * n0;
        ax += bf_lo(u1) * n1; ay += bf_hi(u1) * n1;
        ax += bf_lo(u2) * n2; ay += bf_hi(u2) * n2;
        ax += bf_lo(u3) * n3; ay += bf_hi(u3) * n3;
    }
    for (; i < end; i++) {
        int2 e = csr[i];
        unsigned int ue = hwb[e.x * 64 + lane];
        float nm = __int_as_float(e.y);
        ax += bf_lo(ue) * nm; ay += bf_hi(ue) * nm;
    }
    float2 o = {ax, ay};
    ((float2*)agg)[n * 64 + lane] = o;
}

// ======== pooling: block-local segment reduction (batch is sorted) ========
__global__ __launch_bounds__(256) void pool_kernel(const float* __restrict__ h,
                                                   const float* __restrict__ b4,
                                                   const int* __restrict__ batch,
                                                   float* __restrict__ pooled,
                                                   float* __restrict__ cnt) {
    __shared__ int bs[POOL_NODES];
    const int tid = threadIdx.x;
    const int n0 = blockIdx.x * POOL_NODES;
    for (int i = tid; i < POOL_NODES; i += 256) bs[i] = batch[n0 + i];
    __syncthreads();
    const int c2 = tid & 63;
    const int rsub = tid >> 6;  // 0..3
    const float2* __restrict__ h2 = (const float2*)h;
    float2 bb = ((const float2*)b4)[c2];
    float2 acc = {0.f, 0.f};
    float cacc = 0.f;
    int curg = bs[rsub];
    for (int r = rsub; r < POOL_NODES; r += 4) {
        int g = bs[r];
        if (g != curg) {
            atomicAdd(&pooled[curg * H + c2 * 2], acc.x);
            atomicAdd(&pooled[curg * H + c2 * 2 + 1], acc.y);
            if (c2 == 0) atomicAdd(&cnt[curg], cacc);
            acc.x = acc.y = 0.f;
            cacc = 0.f;
            curg = g;
        }
        float2 v = h2[(long)(n0 + r) * 64 + c2];
        acc.x += v.x + bb.x;
        acc.y += v.y + bb.y;
        cacc += 1.f;
    }
    atomicAdd(&pooled[curg * H + c2 * 2], acc.x);
    atomicAdd(&pooled[curg * H + c2 * 2 + 1], acc.y);
    if (c2 == 0) atomicAdd(&cnt[curg], cacc);
}

// ================= final MLP (single block) =================
__global__ __launch_bounds__(1024) void mlp_kernel(const float* __restrict__ pooled,
                                                   const float* __restrict__ cnt,
                                                   const float* __restrict__ lw1,
                                                   const float* __restrict__ lb1,
                                                   const float* __restrict__ lw2,
                                                   const float* __restrict__ lb2,
                                                   float* __restrict__ out) {
    __shared__ float mean_s[NG * H];
    __shared__ float hid_s[NG * 64];
    int tid = threadIdx.x;
    for (int i = tid; i < NG * H; i += 1024) {
        int g = i >> 7;
        mean_s[i] = pooled[i] / fmaxf(cnt[g], 1.0f);
    }
    __syncthreads();
    {
        int g = tid >> 6, j = tid & 63;
        float acc = lb1[j];
        for (int f = 0; f < H; f++) acc += mean_s[g * H + f] * lw1[f * 64 + j];
        hid_s[g * 64 + j] = fmaxf(acc, 0.f);
    }
    __syncthreads();
    if (tid < 32) {
        int g = tid >> 1, c = tid & 1;
        float acc = lb2[c];
        for (int j = 0; j < 64; j++) acc += hid_s[g * 64 + j] * lw2[j * 2 + c];
        out[g * 2 + c] = acc;
    }
}

extern "C" void kernel_launch(void* const* d_in, const int* in_sizes, int n_in,
                              void* d_out, int out_size, void* d_ws, size_t ws_size,
                              hipStream_t stream) {
    const float* x = (const float*)d_in[0];
    const int* ei = (const int*)d_in[1];
    const int* batch = (const int*)d_in[2];
    const float* W1 = (const float*)d_in[3];
    const float* b1 = (const float*)d_in[4];
    const float* W2 = (const float*)d_in[5];
    const float* b2 = (const float*)d_in[6];
    const float* W3 = (const float*)d_in[7];
    const float* b3 = (const float*)d_in[8];
    const float* W4 = (const float*)d_in[9];
    const float* b4 = (const float*)d_in[10];
    const float* lw1 = (const float*)d_in[11];
    const float* lb1 = (const float*)d_in[12];
    const float* lw2 = (const float*)d_in[13];
    const float* lb2 = (const float*)d_in[14];
    float* out = (float*)d_out;

    // workspace layout (4-byte units, 16-elem aligned blocks)
    int* wsi = (int*)d_ws;
    int* cnt = wsi;                              // [0, 50048)
    int* bsum = wsi + 50048;                     // 256
    int* rowptr = wsi + 50304;                   // NN+1 (50016 pad)
    int* cursor = wsi + 100320;                  // 50048
    int2* csr = (int2*)(wsi + 150368);           // NE int2 = 1600000 ints
    float* dinv = (float*)(wsi + 1750368);       // 50048
    unsigned int* hwb = (unsigned int*)(wsi + 1800416);  // NN*64 uints (bf16x2)
    float* bufB = (float*)(wsi + 5000416);       // NN*H floats
    float* pooled = (float*)(wsi + 11400416);    // NG*H
    float* pcnt = pooled + NG * H;               // NG

    const int nodeBlocks = (NN + 255) / 256;   // 196
    const int edgeBlocks = (NE + 255) / 256;   // 3125
    const int gemmBlocks = NN / 16;            // 3125
    const int aggBlocks = NN / 4;              // 12500

    // ---- CSR build (once; reused by all 4 layers) ----
    hipMemsetAsync(cnt, 0, NN * sizeof(int), stream);
    hist_kernel<<<edgeBlocks, 256, 0, stream>>>(ei + NE, cnt);
    scanA_kernel<<<SCAN_BLOCKS, 256, 0, stream>>>(cnt, bsum);
    scanB_kernel<<<1, 256, 0, stream>>>(bsum);
    scanC_kernel<<<SCAN_BLOCKS, 256, 0, stream>>>(cnt, bsum, rowptr, cursor);
    dinv_kernel<<<nodeBlocks, 256, 0, stream>>>(cnt, dinv);
    fill_kernel<<<edgeBlocks, 256, 0, stream>>>(ei, dinv, cursor, csr);

    // ---- layer 1 (K=64, input x) ----
    gemm_kernel<FIN><<<gemmBlocks, 256, 0, stream>>>(x, W1, nullptr, hwb);
    agg_kernel<<<aggBlocks, 256, 0, stream>>>(hwb, rowptr, csr, dinv, bufB);

    // ---- layer 2 (fused relu(h + b1) on GEMM input read) ----
    gemm_kernel<H><<<gemmBlocks, 256, 0, stream>>>(bufB, W2, b1, hwb);
    agg_kernel<<<aggBlocks, 256, 0, stream>>>(hwb, rowptr, csr, dinv, bufB);

    // ---- layer 3 ----
    gemm_kernel<H><<<gemmBlocks, 256, 0, stream>>>(bufB, W3, b2, hwb);
    agg_kernel<<<aggBlocks, 256, 0, stream>>>(hwb, rowptr, csr, dinv, bufB);

    // ---- layer 4 ----
    gemm_kernel<H><<<gemmBlocks, 256, 0, stream>>>(bufB, W4, b3, hwb);
    agg_kernel<<<aggBlocks, 256, 0, stream>>>(hwb, rowptr, csr, dinv, bufB);

    // ---- pooling (fused +b4) + MLP ----
    hipMemsetAsync(pooled, 0, (NG * H + NG) * sizeof(float), stream);
    pool_kernel<<<POOL_BLOCKS, 256, 0, stream>>>(bufB, b4, batch, pooled, pcnt);
    mlp_kernel<<<1, 1024, 0, stream>>>(pooled, pcnt, lw1, lb1, lw2, lb2, out);
}

// Round 5
// 474.689 us; speedup vs baseline: 13.6186x; 1.0729x over previous
//
#include <hip/hip_runtime.h>

#define NN 50000
#define NPAD 50048   // rows padded to multiple of 64 for MFMA tiles
#define NE 800000
#define FIN 64
#define H 128
#define NG 16
#define POOL_BLOCKS 200
#define POOL_NODES 250
#define SCAN_BLOCKS 196  // ceil(NN/256)

typedef __bf16 bf16x8 __attribute__((ext_vector_type(8)));
typedef float f32x4 __attribute__((ext_vector_type(4)));

// ---- helpers ----
__device__ inline unsigned short bf16r(float x) {
    unsigned int u = __float_as_uint(x);
    return (unsigned short)((u + 0x7fffu + ((u >> 16) & 1u)) >> 16);
}
__device__ inline unsigned int pack_bf16x2(float a, float b) {
    return (unsigned int)bf16r(a) | ((unsigned int)bf16r(b) << 16);
}
__device__ inline float bf_lo(unsigned int u) { return __uint_as_float(u << 16); }
__device__ inline float bf_hi(unsigned int u) { return __uint_as_float(u & 0xffff0000u); }

// ================= CSR build =================
__global__ __launch_bounds__(256) void hist_kernel(const int* __restrict__ dst,
                                                   int* __restrict__ cnt) {
    int e = blockIdx.x * 256 + threadIdx.x;
    if (e < NE) atomicAdd(&cnt[dst[e]], 1);
}

__global__ __launch_bounds__(256) void scanA_kernel(const int* __restrict__ cnt,
                                                    int* __restrict__ bsum) {
    __shared__ int red[4];
    int i = blockIdx.x * 256 + threadIdx.x;
    int v = (i < NN) ? cnt[i] : 0;
    for (int off = 32; off > 0; off >>= 1) v += __shfl_down(v, off);
    if ((threadIdx.x & 63) == 0) red[threadIdx.x >> 6] = v;
    __syncthreads();
    if (threadIdx.x == 0) bsum[blockIdx.x] = red[0] + red[1] + red[2] + red[3];
}

__global__ __launch_bounds__(256) void scanB_kernel(int* __restrict__ bsum) {
    __shared__ int s[256];
    int t = threadIdx.x;
    int v = (t < SCAN_BLOCKS) ? bsum[t] : 0;
    s[t] = v;
    __syncthreads();
    for (int off = 1; off < 256; off <<= 1) {
        int u = (t >= off) ? s[t - off] : 0;
        __syncthreads();
        s[t] += u;
        __syncthreads();
    }
    if (t < SCAN_BLOCKS) bsum[t] = s[t] - v;  // exclusive
}

__global__ __launch_bounds__(256) void scanC_kernel(const int* __restrict__ cnt,
                                                    const int* __restrict__ bsum,
                                                    int* __restrict__ rowptr,
                                                    int* __restrict__ cursor) {
    __shared__ int s[256];
    int t = threadIdx.x;
    int i = blockIdx.x * 256 + t;
    int v = (i < NN) ? cnt[i] : 0;
    s[t] = v;
    __syncthreads();
    for (int off = 1; off < 256; off <<= 1) {
        int u = (t >= off) ? s[t - off] : 0;
        __syncthreads();
        s[t] += u;
        __syncthreads();
    }
    if (i < NN) {
        int ex = bsum[blockIdx.x] + s[t] - v;
        rowptr[i] = ex;
        cursor[i] = ex;
    }
    if (i == NN - 1) rowptr[NN] = NE;
}

__global__ __launch_bounds__(256) void dinv_kernel(const int* __restrict__ cnt,
                                                   float* __restrict__ dinv) {
    int i = blockIdx.x * 256 + threadIdx.x;
    if (i < NN) dinv[i] = rsqrtf((float)cnt[i] + 1.0f);  // +1 self-loop
}

// fill: src index only (norm folded into gemm/agg epilogues)
__global__ __launch_bounds__(256) void fill_kernel(const int* __restrict__ ei,
                                                   int* __restrict__ cursor,
                                                   int* __restrict__ csr) {
    int e = blockIdx.x * 256 + threadIdx.x;
    if (e >= NE) return;
    int s = ei[e], d = ei[NE + e];
    int pos = atomicAdd(&cursor[d], 1);
    csr[pos] = s;
}

// ================= converts =================
__global__ __launch_bounds__(256) void cvt_x_kernel(const float* __restrict__ x,
                                                    unsigned short* __restrict__ xb) {
    int e = blockIdx.x * 256 + threadIdx.x;  // NPAD*64
    if (e >= NPAD * FIN) return;
    xb[e] = (e < NN * FIN) ? bf16r(x[e]) : (unsigned short)0;
}

// Wt[n*K+k] = bf16(W[k*H + n])  (transpose + convert; weights are tiny)
template <int K>
__global__ __launch_bounds__(256) void cvt_w_kernel(const float* __restrict__ W,
                                                    unsigned short* __restrict__ Wt) {
    int t = blockIdx.x * 256 + threadIdx.x;  // H*K
    if (t >= H * K) return;
    int n = t / K, k = t % K;
    Wt[t] = bf16r(W[k * H + n]);
}

// ===== MFMA GEMM: out_bf16[NPAD,H] = (h_bf16[NPAD,K] @ W[K,H]) * dinv[row] =====
// block = 4 waves = 64 rows; per wave: 16 rows x 8 col-tiles of 16, K-loop K/32.
// A frag: A[m=lane&15][k=quad*8+j]; B frag from Wt[n][k] (k contiguous);
// C/D: col=lane&15, row=quad*4+reg.
template <int K>
__global__ __launch_bounds__(256) void gemm_mfma_kernel(const unsigned short* __restrict__ hb,
                                                        const unsigned short* __restrict__ Wt,
                                                        const float* __restrict__ dinv,
                                                        unsigned short* __restrict__ out) {
    const int wave = threadIdx.x >> 6, lane = threadIdx.x & 63;
    const int m15 = lane & 15, quad = lane >> 4;
    const int arow = blockIdx.x * 64 + wave * 16 + m15;

    bf16x8 a[K / 32];
#pragma unroll
    for (int ks = 0; ks < K / 32; ks++)
        a[ks] = *(const bf16x8*)&hb[(size_t)arow * K + ks * 32 + quad * 8];

    const int rbase = blockIdx.x * 64 + wave * 16 + quad * 4;
    float dv[4];
#pragma unroll
    for (int r = 0; r < 4; r++) dv[r] = dinv[rbase + r];

#pragma unroll
    for (int ct = 0; ct < 8; ct++) {
        f32x4 acc = {0.f, 0.f, 0.f, 0.f};
#pragma unroll
        for (int ks = 0; ks < K / 32; ks++) {
            bf16x8 b = *(const bf16x8*)&Wt[(ct * 16 + m15) * K + ks * 32 + quad * 8];
            acc = __builtin_amdgcn_mfma_f32_16x16x32_bf16(a[ks], b, acc, 0, 0, 0);
        }
#pragma unroll
        for (int r = 0; r < 4; r++)
            out[(size_t)(rbase + r) * H + ct * 16 + m15] = bf16r(acc[r] * dv[r]);
    }
}

// ============ gather-side aggregation (pure sum; norms prescaled) ============
// hwb holds hw' = (h@W)*dinv_row (bf16x2 per uint). One wave per dst node.
// agg_raw = (hw'[n] + sum_e hw'[src_e]) * dinv[n]
// RELU_BIAS: out_bf16 = relu(agg_raw + b); else out_bf16 = agg_raw.
template <bool RELU_BIAS>
__global__ __launch_bounds__(256) void agg_kernel(const unsigned int* __restrict__ hwb,
                                                  const int* __restrict__ rowptr,
                                                  const int* __restrict__ csr,
                                                  const float* __restrict__ dinv,
                                                  const float* __restrict__ bias,
                                                  unsigned int* __restrict__ outb) {
    const int lane = threadIdx.x & 63;
    const int n = blockIdx.x * 4 + (threadIdx.x >> 6);

    unsigned int u = hwb[n * 64 + lane];
    float ax = bf_lo(u), ay = bf_hi(u);

    int beg = rowptr[n], end = rowptr[n + 1];
    int i = beg;
    for (; i + 8 <= end; i += 8) {
        int s0 = csr[i], s1 = csr[i + 1], s2 = csr[i + 2], s3 = csr[i + 3];
        int s4 = csr[i + 4], s5 = csr[i + 5], s6 = csr[i + 6], s7 = csr[i + 7];
        unsigned int u0 = hwb[s0 * 64 + lane], u1 = hwb[s1 * 64 + lane];
        unsigned int u2 = hwb[s2 * 64 + lane], u3 = hwb[s3 * 64 + lane];
        unsigned int u4 = hwb[s4 * 64 + lane], u5 = hwb[s5 * 64 + lane];
        unsigned int u6 = hwb[s6 * 64 + lane], u7 = hwb[s7 * 64 + lane];
        ax += bf_lo(u0) + bf_lo(u1) + bf_lo(u2) + bf_lo(u3) +
              bf_lo(u4) + bf_lo(u5) + bf_lo(u6) + bf_lo(u7);
        ay += bf_hi(u0) + bf_hi(u1) + bf_hi(u2) + bf_hi(u3) +
              bf_hi(u4) + bf_hi(u5) + bf_hi(u6) + bf_hi(u7);
    }
    for (; i < end; i++) {
        unsigned int ue = hwb[csr[i] * 64 + lane];
        ax += bf_lo(ue);
        ay += bf_hi(ue);
    }
    float d = dinv[n];
    ax *= d;
    ay *= d;
    if (RELU_BIAS) {
        float2 bv = ((const float2*)bias)[lane];
        ax = fmaxf(ax + bv.x, 0.f);
        ay = fmaxf(ay + bv.y, 0.f);
    }
    outb[n * 64 + lane] = pack_bf16x2(ax, ay);
}

// ======== pooling: block-local segment reduction (batch sorted), bf16 in ========
__global__ __launch_bounds__(256) void pool_kernel(const unsigned int* __restrict__ hbu,
                                                   const float* __restrict__ b4,
                                                   const int* __restrict__ batch,
                                                   float* __restrict__ pooled,
                                                   float* __restrict__ cnt) {
    __shared__ int bs[POOL_NODES];
    const int tid = threadIdx.x;
    const int n0 = blockIdx.x * POOL_NODES;
    for (int i = tid; i < POOL_NODES; i += 256) bs[i] = batch[n0 + i];
    __syncthreads();
    const int c2 = tid & 63;
    const int rsub = tid >> 6;  // 0..3
    float2 bb = ((const float2*)b4)[c2];
    float2 acc = {0.f, 0.f};
    float cacc = 0.f;
    int curg = bs[rsub];
    for (int r = rsub; r < POOL_NODES; r += 4) {
        int g = bs[r];
        if (g != curg) {
            atomicAdd(&pooled[curg * H + c2 * 2], acc.x);
            atomicAdd(&pooled[curg * H + c2 * 2 + 1], acc.y);
            if (c2 == 0) atomicAdd(&cnt[curg], cacc);
            acc.x = acc.y = 0.f;
            cacc = 0.f;
            curg = g;
        }
        unsigned int v = hbu[(size_t)(n0 + r) * 64 + c2];
        acc.x += bf_lo(v) + bb.x;
        acc.y += bf_hi(v) + bb.y;
        cacc += 1.f;
    }
    atomicAdd(&pooled[curg * H + c2 * 2], acc.x);
    atomicAdd(&pooled[curg * H + c2 * 2 + 1], acc.y);
    if (c2 == 0) atomicAdd(&cnt[curg], cacc);
}

// ================= final MLP (single block) =================
__global__ __launch_bounds__(1024) void mlp_kernel(const float* __restrict__ pooled,
                                                   const float* __restrict__ cnt,
                                                   const float* __restrict__ lw1,
                                                   const float* __restrict__ lb1,
                                                   const float* __restrict__ lw2,
                                                   const float* __restrict__ lb2,
                                                   float* __restrict__ out) {
    __shared__ float mean_s[NG * H];
    __shared__ float hid_s[NG * 64];
    int tid = threadIdx.x;
    for (int i = tid; i < NG * H; i += 1024) {
        int g = i >> 7;
        mean_s[i] = pooled[i] / fmaxf(cnt[g], 1.0f);
    }
    __syncthreads();
    {
        int g = tid >> 6, j = tid & 63;
        float acc = lb1[j];
        for (int f = 0; f < H; f++) acc += mean_s[g * H + f] * lw1[f * 64 + j];
        hid_s[g * 64 + j] = fmaxf(acc, 0.f);
    }
    __syncthreads();
    if (tid < 32) {
        int g = tid >> 1, c = tid & 1;
        float acc = lb2[c];
        for (int j = 0; j < 64; j++) acc += hid_s[g * 64 + j] * lw2[j * 2 + c];
        out[g * 2 + c] = acc;
    }
}

extern "C" void kernel_launch(void* const* d_in, const int* in_sizes, int n_in,
                              void* d_out, int out_size, void* d_ws, size_t ws_size,
                              hipStream_t stream) {
    const float* x = (const float*)d_in[0];
    const int* ei = (const int*)d_in[1];
    const int* batch = (const int*)d_in[2];
    const float* W1 = (const float*)d_in[3];
    const float* b1 = (const float*)d_in[4];
    const float* W2 = (const float*)d_in[5];
    const float* b2 = (const float*)d_in[6];
    const float* W3 = (const float*)d_in[7];
    const float* b3 = (const float*)d_in[8];
    const float* W4 = (const float*)d_in[9];
    const float* b4 = (const float*)d_in[10];
    const float* lw1 = (const float*)d_in[11];
    const float* lb1 = (const float*)d_in[12];
    const float* lw2 = (const float*)d_in[13];
    const float* lb2 = (const float*)d_in[14];
    float* out = (float*)d_out;

    // workspace layout (4-byte units); total ~36.2 MB
    int* wsi = (int*)d_ws;
    int* cnt = wsi;                                        // 50048
    int* bsum = wsi + 50048;                               // 256
    int* rowptr = wsi + 50304;                             // 50016
    int* cursor = wsi + 100320;                            // 50048
    int* csr = wsi + 150368;                               // NE
    float* dinv = (float*)(wsi + 950368);                  // 50048
    unsigned short* Wt1 = (unsigned short*)(wsi + 1000416);  // 128*64
    unsigned short* Wt2 = (unsigned short*)(wsi + 1004512);  // 128*128
    unsigned short* Wt3 = (unsigned short*)(wsi + 1012704);
    unsigned short* Wt4 = (unsigned short*)(wsi + 1020896);
    unsigned short* xb = (unsigned short*)(wsi + 1029088);   // NPAD*64
    unsigned int* hb = (unsigned int*)(wsi + 2630624);       // NPAD*64 (bf16x2)
    unsigned int* hwb = (unsigned int*)(wsi + 5833696);      // NPAD*64
    float* pooled = (float*)(wsi + 9036768);                 // NG*H
    float* pcnt = pooled + NG * H;                           // NG

    const int nodeBlocks = (NN + 255) / 256;   // 196
    const int edgeBlocks = (NE + 255) / 256;   // 3125
    const int gemmBlocks = NPAD / 64;          // 782
    const int aggBlocks = NN / 4;              // 12500

    // ---- CSR build (once; reused by all 4 layers) ----
    hipMemsetAsync(cnt, 0, NN * sizeof(int), stream);
    hist_kernel<<<edgeBlocks, 256, 0, stream>>>(ei + NE, cnt);
    scanA_kernel<<<SCAN_BLOCKS, 256, 0, stream>>>(cnt, bsum);
    scanB_kernel<<<1, 256, 0, stream>>>(bsum);
    scanC_kernel<<<SCAN_BLOCKS, 256, 0, stream>>>(cnt, bsum, rowptr, cursor);
    dinv_kernel<<<nodeBlocks, 256, 0, stream>>>(cnt, dinv);
    fill_kernel<<<edgeBlocks, 256, 0, stream>>>(ei, cursor, csr);

    // ---- converts ----
    cvt_x_kernel<<<(NPAD * FIN) / 256, 256, 0, stream>>>(x, xb);
    cvt_w_kernel<FIN><<<(H * FIN) / 256, 256, 0, stream>>>(W1, Wt1);
    cvt_w_kernel<H><<<(H * H) / 256, 256, 0, stream>>>(W2, Wt2);
    cvt_w_kernel<H><<<(H * H) / 256, 256, 0, stream>>>(W3, Wt3);
    cvt_w_kernel<H><<<(H * H) / 256, 256, 0, stream>>>(W4, Wt4);

    // ---- layer 1 ----
    gemm_mfma_kernel<FIN><<<gemmBlocks, 256, 0, stream>>>(xb, Wt1, dinv, (unsigned short*)hwb);
    agg_kernel<true><<<aggBlocks, 256, 0, stream>>>(hwb, rowptr, csr, dinv, b1, hb);
    // ---- layer 2 ----
    gemm_mfma_kernel<H><<<gemmBlocks, 256, 0, stream>>>((unsigned short*)hb, Wt2, dinv, (unsigned short*)hwb);
    agg_kernel<true><<<aggBlocks, 256, 0, stream>>>(hwb, rowptr, csr, dinv, b2, hb);
    // ---- layer 3 ----
    gemm_mfma_kernel<H><<<gemmBlocks, 256, 0, stream>>>((unsigned short*)hb, Wt3, dinv, (unsigned short*)hwb);
    agg_kernel<true><<<aggBlocks, 256, 0, stream>>>(hwb, rowptr, csr, dinv, b3, hb);
    // ---- layer 4 (no relu/bias; b4 fused in pool) ----
    gemm_mfma_kernel<H><<<gemmBlocks, 256, 0, stream>>>((unsigned short*)hb, Wt4, dinv, (unsigned short*)hwb);
    agg_kernel<false><<<aggBlocks, 256, 0, stream>>>(hwb, rowptr, csr, dinv, nullptr, hb);

    // ---- pooling (fused +b4) + MLP ----
    hipMemsetAsync(pooled, 0, (NG * H + NG) * sizeof(float), stream);
    pool_kernel<<<POOL_BLOCKS, 256, 0, stream>>>(hb, b4, batch, pooled, pcnt);
    mlp_kernel<<<1, 1024, 0, stream>>>(pooled, pcnt, lw1, lb1, lw2, lb2, out);
}